// Round 15
// baseline (55.186 us; speedup 1.0000x reference)
//
#include <hip/hip_runtime.h>

// MLP: 30->24->19->14->10->6->2->1, ReLU between all but last layer.
// f16-pair compute: v_dot2_f32_f16 (2 MACs/instr, fp32 accumulate).
// R15 changes vs R14 (which was latency/occupancy-bound: 26% occ, 39% VALU):
//  - __launch_bounds__(256,4): grid is exactly 1024 blocks; 4 blocks/CU makes
//    ALL blocks co-resident in one round (R14's (256,3) left a 256-block
//    straggler round at 12.5% occupancy).
//  - ReLU fused into packed f16: pack then v_pk_max_f16 (1 op/pair instead
//    of 2 scalar fmaxf).
//  - x converted float4 -> h2 pairs directly (no ta/tb f32 temp arrays).
// Structure kept: weights f16 in LDS (rows padded to 8-f16 multiples ->
// ds_read_b128 broadcasts), 4 ADJACENT rows/thread (480B one-touch x
// footprint -> 30 dwordx4; each weight read feeds 4 rows).

#define NTHREADS 256

using h2 = __fp16 __attribute__((ext_vector_type(2)));

__device__ __forceinline__ float fdot2f(h2 a, h2 b, float c) {
#if defined(__has_builtin) && __has_builtin(__builtin_amdgcn_fdot2)
    return __builtin_amdgcn_fdot2(a, b, c, false);
#else
    return fmaf((float)a.x, (float)b.x, fmaf((float)a.y, (float)b.y, c));
#endif
}

__device__ __forceinline__ h2 pk2(float a, float b) {
#if defined(__has_builtin) && __has_builtin(__builtin_amdgcn_cvt_pkrtz)
    return __builtin_bit_cast(h2, __builtin_amdgcn_cvt_pkrtz(a, b));
#else
    h2 r; r.x = (__fp16)a; r.y = (__fp16)b; return r;
#endif
}

__device__ __forceinline__ h2 h2zero() { h2 z; z.x = (__fp16)0.f; z.y = (__fp16)0.f; return z; }
__device__ __forceinline__ h2 bch2(float f) { return __builtin_bit_cast(h2, f); }
__device__ __forceinline__ h2 relu2(h2 v) {
#if defined(__has_builtin) && __has_builtin(__builtin_elementwise_max)
    return __builtin_elementwise_max(v, h2zero());
#else
    v.x = v.x > (__fp16)0.f ? v.x : (__fp16)0.f;
    v.y = v.y > (__fp16)0.f ? v.y : (__fp16)0.f;
    return v;
#endif
}

// f16 LDS weight layout (units = __fp16), rows padded to multiples of 8:
//  W1@0:24x32  W2@768:19x24  W3@1224:14x24  W4@1560:10x16
//  W5@1720:6x16  W6@1816:2x8  W7@1832:1x8  -> 1840 f16 = 3680 B
// biases (f32): b1@0(24) b2@24(19) b3@43(14) b4@57(10) b5@67(6) b6@73(2) b7@75

template <int FIN, int PADH, int FOUT>
__device__ __forceinline__ void stage_wh(const float* __restrict__ g, __fp16* __restrict__ s, int t) {
    for (int idx = t; idx < FOUT * PADH; idx += NTHREADS) {
        int r = idx / PADH;
        int c = idx - r * PADH;
        s[idx] = (c < FIN) ? (__fp16)g[r * FIN + c] : (__fp16)0.f;
    }
}

// One layer, 4 rows at once. in: [4][PADH/2] h2 pairs (pads zeroed).
// out: [4][OUTP] h2 pairs (pads zeroed). fp32 acc + bias; relu in packed f16.
template <int PADH, int FOUT, int OUTP, bool RELU>
__device__ __forceinline__ void layer_dot4(const __fp16* __restrict__ wl,
                                           const float* __restrict__ bl,
                                           const h2* __restrict__ in,    // stride PADH/2
                                           h2* __restrict__ outp)        // stride OUTP
{
    constexpr int INP = PADH / 2;
    constexpr int CH  = PADH / 8;
    constexpr int JP  = (FOUT + 1) / 2;
#pragma unroll
    for (int jp = 0; jp < JP; ++jp) {
        const int j0 = 2 * jp, j1 = 2 * jp + 1;
        float a0[4], a1[4];
#pragma unroll
        for (int r = 0; r < 4; ++r) {
            a0[r] = bl[j0];
            a1[r] = (j1 < FOUT) ? bl[j1] : 0.0f;
        }
        const float4* w0p = (const float4*)(wl + j0 * PADH);
        const float4* w1p = (const float4*)(wl + (j1 < FOUT ? j1 : j0) * PADH);
#pragma unroll
        for (int c = 0; c < CH; ++c) {
            float4 wa = w0p[c];
            h2 wa0 = bch2(wa.x), wa1 = bch2(wa.y), wa2 = bch2(wa.z), wa3 = bch2(wa.w);
            h2 wb0, wb1, wb2, wb3;
            if (j1 < FOUT) {
                float4 wb = w1p[c];
                wb0 = bch2(wb.x); wb1 = bch2(wb.y); wb2 = bch2(wb.z); wb3 = bch2(wb.w);
            }
#pragma unroll
            for (int r = 0; r < 4; ++r) {
                const h2* ir = in + r * INP + 4 * c;
                a0[r] = fdot2f(wa0, ir[0], a0[r]);
                a0[r] = fdot2f(wa1, ir[1], a0[r]);
                a0[r] = fdot2f(wa2, ir[2], a0[r]);
                a0[r] = fdot2f(wa3, ir[3], a0[r]);
                if (j1 < FOUT) {
                    a1[r] = fdot2f(wb0, ir[0], a1[r]);
                    a1[r] = fdot2f(wb1, ir[1], a1[r]);
                    a1[r] = fdot2f(wb2, ir[2], a1[r]);
                    a1[r] = fdot2f(wb3, ir[3], a1[r]);
                }
            }
        }
#pragma unroll
        for (int r = 0; r < 4; ++r) {
            h2 pv = pk2(a0[r], (j1 < FOUT) ? a1[r] : 0.0f);
            if (RELU) pv = relu2(pv);       // packed relu; pads stay 0
            outp[r * OUTP + jp] = pv;
        }
    }
#pragma unroll
    for (int jp = JP; jp < OUTP; ++jp)
#pragma unroll
        for (int r = 0; r < 4; ++r) outp[r * OUTP + jp] = h2zero();
}

__global__ __launch_bounds__(NTHREADS, 4) void mlp_dot2b(
    const float* __restrict__ x,
    const float* __restrict__ W1, const float* __restrict__ B1,
    const float* __restrict__ W2, const float* __restrict__ B2,
    const float* __restrict__ W3, const float* __restrict__ B3,
    const float* __restrict__ W4, const float* __restrict__ B4,
    const float* __restrict__ W5, const float* __restrict__ B5,
    const float* __restrict__ W6, const float* __restrict__ B6,
    const float* __restrict__ W7, const float* __restrict__ B7,
    float* __restrict__ out, int nrows)
{
    __shared__ __fp16 sh[1840];
    __shared__ float  sb[76];
    const int t = threadIdx.x;

    stage_wh<30, 32, 24>(W1, sh + 0,    t);
    stage_wh<24, 24, 19>(W2, sh + 768,  t);
    stage_wh<19, 24, 14>(W3, sh + 1224, t);
    stage_wh<14, 16, 10>(W4, sh + 1560, t);
    stage_wh<10, 16, 6 >(W5, sh + 1720, t);
    stage_wh<6,  8,  2 >(W6, sh + 1816, t);
    stage_wh<2,  8,  1 >(W7, sh + 1832, t);
    if (t < 24) sb[0  + t] = B1[t];
    if (t < 19) sb[24 + t] = B2[t];
    if (t < 14) sb[43 + t] = B3[t];
    if (t < 10) sb[57 + t] = B4[t];
    if (t < 6)  sb[67 + t] = B5[t];
    if (t < 2)  sb[73 + t] = B6[t];
    if (t < 1)  sb[75 + t] = B7[t];
    __syncthreads();

    const int row0 = (blockIdx.x * NTHREADS + t) * 4;   // 4 adjacent rows
    if (row0 + 3 >= nrows) return;

    // ---- up-front x load: 480 B contiguous = 30 dwordx4 -> h2 pairs ----
    // Global pair p (p=0..59): row = p/15, slot = p%15. float4 i gives
    // pairs 2i (v.x,v.y) and 2i+1 (v.z,v.w); indices constant after unroll.
    h2 xq[4 * 16];                                      // [r][16], pair 15 = zero pad
    {
        const float4* xp = (const float4*)(x + (size_t)row0 * 30);
#pragma unroll
        for (int i = 0; i < 30; ++i) {
            float4 v = xp[i];
            const int p0 = 2 * i, p1 = 2 * i + 1;
            xq[(p0 / 15) * 16 + (p0 % 15)] = pk2(v.x, v.y);
            xq[(p1 / 15) * 16 + (p1 % 15)] = pk2(v.z, v.w);
        }
#pragma unroll
        for (int r = 0; r < 4; ++r) xq[r * 16 + 15] = h2zero();
    }

    h2 h1[4 * 12];  layer_dot4<32, 24, 12, true>(sh + 0,    sb + 0,  xq,  h1);
    h2 h2a[4 * 12]; layer_dot4<24, 19, 12, true>(sh + 768,  sb + 24, h1,  h2a);
    h2 h3[4 * 8];   layer_dot4<24, 14, 8,  true>(sh + 1224, sb + 43, h2a, h3);
    h2 h4[4 * 8];   layer_dot4<16, 10, 8,  true>(sh + 1560, sb + 57, h3,  h4);
    h2 h5[4 * 4];   layer_dot4<16, 6,  4,  true>(sh + 1720, sb + 67, h4,  h5);
    h2 h6[4 * 1];   layer_dot4<8,  2,  1,  true>(sh + 1816, sb + 73, h5,  h6);

    // ---- layer 7: 2 -> 1, no relu ----
    const h2 w7 = *(const h2*)(sh + 1832);
    const float b7 = sb[75];
    float o[4];
#pragma unroll
    for (int r = 0; r < 4; ++r) o[r] = fdot2f(w7, h6[r], b7);

    *(float4*)(out + row0) = make_float4(o[0], o[1], o[2], o[3]);
}

extern "C" void kernel_launch(void* const* d_in, const int* in_sizes, int n_in,
                              void* d_out, int out_size, void* d_ws, size_t ws_size,
                              hipStream_t stream) {
    const float* x = (const float*)d_in[0];
    int nrows = in_sizes[0] / 30;
    int quads = nrows / 4;
    int blocks = (quads + NTHREADS - 1) / NTHREADS;
    mlp_dot2b<<<blocks, NTHREADS, 0, stream>>>(
        x,
        (const float*)d_in[1],  (const float*)d_in[2],
        (const float*)d_in[3],  (const float*)d_in[4],
        (const float*)d_in[5],  (const float*)d_in[6],
        (const float*)d_in[7],  (const float*)d_in[8],
        (const float*)d_in[9],  (const float*)d_in[10],
        (const float*)d_in[11], (const float*)d_in[12],
        (const float*)d_in[13], (const float*)d_in[14],
        (float*)d_out, nrows);
}

// Round 16
// 50.092 us; speedup vs baseline: 1.1017x; 1.1017x over previous
//
#include <hip/hip_runtime.h>

// MLP: 30->24->19->14->10->6->2->1, ReLU between all but last layer.
// f16-pair compute: v_dot2_f32_f16 (2 MACs/instr, fp32 accumulate).
// R16 = R14 structure (best: 51.4us) + exactly two deltas:
//  - __launch_bounds__(256,4): all 1024 blocks co-resident (R14's (256,3)
//    left a 256-block straggler round at 12.5% occupancy -> 26% avg).
//  - packed relu: pack f32 pair -> h2, then one v_pk_max_f16.
// KEPT from R14 (R15 regression lesson): x loaded in TWO TIGHT BURSTS of
// 15 dwordx4 into f32 temps, converted AFTER the burst (one vmcnt wait;
// lines touched while L1-resident; FETCH stays ~63MB).

#define NTHREADS 256

using h2 = __fp16 __attribute__((ext_vector_type(2)));

__device__ __forceinline__ float fdot2f(h2 a, h2 b, float c) {
#if defined(__has_builtin) && __has_builtin(__builtin_amdgcn_fdot2)
    return __builtin_amdgcn_fdot2(a, b, c, false);
#else
    return fmaf((float)a.x, (float)b.x, fmaf((float)a.y, (float)b.y, c));
#endif
}

__device__ __forceinline__ h2 pk2(float a, float b) {
#if defined(__has_builtin) && __has_builtin(__builtin_amdgcn_cvt_pkrtz)
    return __builtin_bit_cast(h2, __builtin_amdgcn_cvt_pkrtz(a, b));
#else
    h2 r; r.x = (__fp16)a; r.y = (__fp16)b; return r;
#endif
}

__device__ __forceinline__ h2 h2zero() { h2 z; z.x = (__fp16)0.f; z.y = (__fp16)0.f; return z; }
__device__ __forceinline__ h2 bch2(float f) { return __builtin_bit_cast(h2, f); }
__device__ __forceinline__ h2 relu2(h2 v) {
#if defined(__has_builtin) && __has_builtin(__builtin_elementwise_max)
    return __builtin_elementwise_max(v, h2zero());
#else
    v.x = v.x > (__fp16)0.f ? v.x : (__fp16)0.f;
    v.y = v.y > (__fp16)0.f ? v.y : (__fp16)0.f;
    return v;
#endif
}

// f16 LDS weight layout (units = __fp16), rows padded to multiples of 8:
//  W1@0:24x32  W2@768:19x24  W3@1224:14x24  W4@1560:10x16
//  W5@1720:6x16  W6@1816:2x8  W7@1832:1x8  -> 1840 f16 = 3680 B
// biases (f32): b1@0(24) b2@24(19) b3@43(14) b4@57(10) b5@67(6) b6@73(2) b7@75

template <int FIN, int PADH, int FOUT>
__device__ __forceinline__ void stage_wh(const float* __restrict__ g, __fp16* __restrict__ s, int t) {
    for (int idx = t; idx < FOUT * PADH; idx += NTHREADS) {
        int r = idx / PADH;
        int c = idx - r * PADH;
        s[idx] = (c < FIN) ? (__fp16)g[r * FIN + c] : (__fp16)0.f;
    }
}

// One layer, 4 rows at once. in: [4][PADH/2] h2 pairs (pads zeroed).
// out: [4][OUTP] h2 pairs (pads zeroed). fp32 acc + bias; relu packed.
template <int PADH, int FOUT, int OUTP, bool RELU>
__device__ __forceinline__ void layer_dot4(const __fp16* __restrict__ wl,
                                           const float* __restrict__ bl,
                                           const h2* __restrict__ in,    // stride PADH/2
                                           h2* __restrict__ outp)        // stride OUTP
{
    constexpr int INP = PADH / 2;
    constexpr int CH  = PADH / 8;
    constexpr int JP  = (FOUT + 1) / 2;
#pragma unroll
    for (int jp = 0; jp < JP; ++jp) {
        const int j0 = 2 * jp, j1 = 2 * jp + 1;
        float a0[4], a1[4];
#pragma unroll
        for (int r = 0; r < 4; ++r) {
            a0[r] = bl[j0];
            a1[r] = (j1 < FOUT) ? bl[j1] : 0.0f;
        }
        const float4* w0p = (const float4*)(wl + j0 * PADH);
        const float4* w1p = (const float4*)(wl + (j1 < FOUT ? j1 : j0) * PADH);
#pragma unroll
        for (int c = 0; c < CH; ++c) {
            float4 wa = w0p[c];
            h2 wa0 = bch2(wa.x), wa1 = bch2(wa.y), wa2 = bch2(wa.z), wa3 = bch2(wa.w);
            h2 wb0, wb1, wb2, wb3;
            if (j1 < FOUT) {
                float4 wb = w1p[c];
                wb0 = bch2(wb.x); wb1 = bch2(wb.y); wb2 = bch2(wb.z); wb3 = bch2(wb.w);
            }
#pragma unroll
            for (int r = 0; r < 4; ++r) {
                const h2* ir = in + r * INP + 4 * c;
                a0[r] = fdot2f(wa0, ir[0], a0[r]);
                a0[r] = fdot2f(wa1, ir[1], a0[r]);
                a0[r] = fdot2f(wa2, ir[2], a0[r]);
                a0[r] = fdot2f(wa3, ir[3], a0[r]);
                if (j1 < FOUT) {
                    a1[r] = fdot2f(wb0, ir[0], a1[r]);
                    a1[r] = fdot2f(wb1, ir[1], a1[r]);
                    a1[r] = fdot2f(wb2, ir[2], a1[r]);
                    a1[r] = fdot2f(wb3, ir[3], a1[r]);
                }
            }
        }
#pragma unroll
        for (int r = 0; r < 4; ++r) {
            h2 pv = pk2(a0[r], (j1 < FOUT) ? a1[r] : 0.0f);
            if (RELU) pv = relu2(pv);       // packed relu; pads stay 0
            outp[r * OUTP + jp] = pv;
        }
    }
#pragma unroll
    for (int jp = JP; jp < OUTP; ++jp)
#pragma unroll
        for (int r = 0; r < 4; ++r) outp[r * OUTP + jp] = h2zero();
}

__global__ __launch_bounds__(NTHREADS, 4) void mlp_dot2c(
    const float* __restrict__ x,
    const float* __restrict__ W1, const float* __restrict__ B1,
    const float* __restrict__ W2, const float* __restrict__ B2,
    const float* __restrict__ W3, const float* __restrict__ B3,
    const float* __restrict__ W4, const float* __restrict__ B4,
    const float* __restrict__ W5, const float* __restrict__ B5,
    const float* __restrict__ W6, const float* __restrict__ B6,
    const float* __restrict__ W7, const float* __restrict__ B7,
    float* __restrict__ out, int nrows)
{
    __shared__ __fp16 sh[1840];
    __shared__ float  sb[76];
    const int t = threadIdx.x;

    stage_wh<30, 32, 24>(W1, sh + 0,    t);
    stage_wh<24, 24, 19>(W2, sh + 768,  t);
    stage_wh<19, 24, 14>(W3, sh + 1224, t);
    stage_wh<14, 16, 10>(W4, sh + 1560, t);
    stage_wh<10, 16, 6 >(W5, sh + 1720, t);
    stage_wh<6,  8,  2 >(W6, sh + 1816, t);
    stage_wh<2,  8,  1 >(W7, sh + 1832, t);
    if (t < 24) sb[0  + t] = B1[t];
    if (t < 19) sb[24 + t] = B2[t];
    if (t < 14) sb[43 + t] = B3[t];
    if (t < 10) sb[57 + t] = B4[t];
    if (t < 6)  sb[67 + t] = B5[t];
    if (t < 2)  sb[73 + t] = B6[t];
    if (t < 1)  sb[75 + t] = B7[t];
    __syncthreads();

    const int row0 = (blockIdx.x * NTHREADS + t) * 4;   // 4 adjacent rows
    if (row0 + 3 >= nrows) return;

    // ---- up-front x load: 480 B contiguous = 30 dwordx4 in 2 tight bursts ----
    h2 xq[4 * 16];                                      // [r][16], pair 15 = zero pad
    {
        const float4* xp = (const float4*)(x + (size_t)row0 * 30);
        // burst 1: rows 0,1 (floats 0..59)
        float ta[60];
#pragma unroll
        for (int i = 0; i < 15; ++i) {
            float4 v = xp[i];
            ta[4 * i] = v.x; ta[4 * i + 1] = v.y; ta[4 * i + 2] = v.z; ta[4 * i + 3] = v.w;
        }
#pragma unroll
        for (int r = 0; r < 2; ++r) {
#pragma unroll
            for (int p = 0; p < 15; ++p)
                xq[r * 16 + p] = pk2(ta[30 * r + 2 * p], ta[30 * r + 2 * p + 1]);
            xq[r * 16 + 15] = h2zero();
        }
        // burst 2: rows 2,3 (floats 60..119)
        float tb[60];
#pragma unroll
        for (int i = 0; i < 15; ++i) {
            float4 v = xp[15 + i];
            tb[4 * i] = v.x; tb[4 * i + 1] = v.y; tb[4 * i + 2] = v.z; tb[4 * i + 3] = v.w;
        }
#pragma unroll
        for (int r = 0; r < 2; ++r) {
#pragma unroll
            for (int p = 0; p < 15; ++p)
                xq[(2 + r) * 16 + p] = pk2(tb[30 * r + 2 * p], tb[30 * r + 2 * p + 1]);
            xq[(2 + r) * 16 + 15] = h2zero();
        }
    }

    h2 h1[4 * 12];  layer_dot4<32, 24, 12, true>(sh + 0,    sb + 0,  xq,  h1);
    h2 h2a[4 * 12]; layer_dot4<24, 19, 12, true>(sh + 768,  sb + 24, h1,  h2a);
    h2 h3[4 * 8];   layer_dot4<24, 14, 8,  true>(sh + 1224, sb + 43, h2a, h3);
    h2 h4[4 * 8];   layer_dot4<16, 10, 8,  true>(sh + 1560, sb + 57, h3,  h4);
    h2 h5[4 * 4];   layer_dot4<16, 6,  4,  true>(sh + 1720, sb + 67, h4,  h5);
    h2 h6[4 * 1];   layer_dot4<8,  2,  1,  true>(sh + 1816, sb + 73, h5,  h6);

    // ---- layer 7: 2 -> 1, no relu ----
    const h2 w7 = *(const h2*)(sh + 1832);
    const float b7 = sb[75];
    float o[4];
#pragma unroll
    for (int r = 0; r < 4; ++r) o[r] = fdot2f(w7, h6[r], b7);

    *(float4*)(out + row0) = make_float4(o[0], o[1], o[2], o[3]);
}

extern "C" void kernel_launch(void* const* d_in, const int* in_sizes, int n_in,
                              void* d_out, int out_size, void* d_ws, size_t ws_size,
                              hipStream_t stream) {
    const float* x = (const float*)d_in[0];
    int nrows = in_sizes[0] / 30;
    int quads = nrows / 4;
    int blocks = (quads + NTHREADS - 1) / NTHREADS;
    mlp_dot2c<<<blocks, NTHREADS, 0, stream>>>(
        x,
        (const float*)d_in[1],  (const float*)d_in[2],
        (const float*)d_in[3],  (const float*)d_in[4],
        (const float*)d_in[5],  (const float*)d_in[6],
        (const float*)d_in[7],  (const float*)d_in[8],
        (const float*)d_in[9],  (const float*)d_in[10],
        (const float*)d_in[11], (const float*)d_in[12],
        (const float*)d_in[13], (const float*)d_in[14],
        (float*)d_out, nrows);
}

// Round 17
// 49.557 us; speedup vs baseline: 1.1136x; 1.0108x over previous
//
#include <hip/hip_runtime.h>

// MLP: 30->24->19->14->10->6->2->1, ReLU between all but last layer.
// f16-pair compute: v_dot2_f32_f16 (2 MACs/instr, fp32 accumulate).
// R17 = R16 structure with 2 ADJACENT rows/thread (was 4):
//  - 2048 blocks, __launch_bounds__(256,8): 8 blocks/CU -> 32 waves/CU,
//    ALL blocks co-resident in ONE round (R16: 1024 blocks capped at 16
//    waves/CU = 50% max, measured 33%, latency-bound at the x burst).
//  - per-thread state halved (xq 16 regs, h-arrays halved, single
//    15-dwordx4 burst) to fit the 64-VGPR cap of 8 waves/EU.
// KEPT: tight load burst into f32 temps, convert after (R15 lesson);
// f16 weights in LDS (wave-uniform b128 broadcasts = free); packed relu.

#define NTHREADS 256

using h2 = __fp16 __attribute__((ext_vector_type(2)));

__device__ __forceinline__ float fdot2f(h2 a, h2 b, float c) {
#if defined(__has_builtin) && __has_builtin(__builtin_amdgcn_fdot2)
    return __builtin_amdgcn_fdot2(a, b, c, false);
#else
    return fmaf((float)a.x, (float)b.x, fmaf((float)a.y, (float)b.y, c));
#endif
}

__device__ __forceinline__ h2 pk2(float a, float b) {
#if defined(__has_builtin) && __has_builtin(__builtin_amdgcn_cvt_pkrtz)
    return __builtin_bit_cast(h2, __builtin_amdgcn_cvt_pkrtz(a, b));
#else
    h2 r; r.x = (__fp16)a; r.y = (__fp16)b; return r;
#endif
}

__device__ __forceinline__ h2 h2zero() { h2 z; z.x = (__fp16)0.f; z.y = (__fp16)0.f; return z; }
__device__ __forceinline__ h2 bch2(float f) { return __builtin_bit_cast(h2, f); }
__device__ __forceinline__ h2 relu2(h2 v) {
#if defined(__has_builtin) && __has_builtin(__builtin_elementwise_max)
    return __builtin_elementwise_max(v, h2zero());
#else
    v.x = v.x > (__fp16)0.f ? v.x : (__fp16)0.f;
    v.y = v.y > (__fp16)0.f ? v.y : (__fp16)0.f;
    return v;
#endif
}

// f16 LDS weight layout (units = __fp16), rows padded to multiples of 8:
//  W1@0:24x32  W2@768:19x24  W3@1224:14x24  W4@1560:10x16
//  W5@1720:6x16  W6@1816:2x8  W7@1832:1x8  -> 1840 f16 = 3680 B
// biases (f32): b1@0(24) b2@24(19) b3@43(14) b4@57(10) b5@67(6) b6@73(2) b7@75

template <int FIN, int PADH, int FOUT>
__device__ __forceinline__ void stage_wh(const float* __restrict__ g, __fp16* __restrict__ s, int t) {
    for (int idx = t; idx < FOUT * PADH; idx += NTHREADS) {
        int r = idx / PADH;
        int c = idx - r * PADH;
        s[idx] = (c < FIN) ? (__fp16)g[r * FIN + c] : (__fp16)0.f;
    }
}

// One layer, 2 rows at once. in: [2][PADH/2] h2 pairs (pads zeroed).
// out: [2][OUTP] h2 pairs (pads zeroed). fp32 acc + bias; relu packed.
template <int PADH, int FOUT, int OUTP, bool RELU>
__device__ __forceinline__ void layer_dot2(const __fp16* __restrict__ wl,
                                           const float* __restrict__ bl,
                                           const h2* __restrict__ in,    // stride PADH/2
                                           h2* __restrict__ outp)        // stride OUTP
{
    constexpr int INP = PADH / 2;
    constexpr int CH  = PADH / 8;
    constexpr int JP  = (FOUT + 1) / 2;
#pragma unroll
    for (int jp = 0; jp < JP; ++jp) {
        const int j0 = 2 * jp, j1 = 2 * jp + 1;
        float a0[2], a1[2];
#pragma unroll
        for (int r = 0; r < 2; ++r) {
            a0[r] = bl[j0];
            a1[r] = (j1 < FOUT) ? bl[j1] : 0.0f;
        }
        const float4* w0p = (const float4*)(wl + j0 * PADH);
        const float4* w1p = (const float4*)(wl + (j1 < FOUT ? j1 : j0) * PADH);
#pragma unroll
        for (int c = 0; c < CH; ++c) {
            float4 wa = w0p[c];
            h2 wa0 = bch2(wa.x), wa1 = bch2(wa.y), wa2 = bch2(wa.z), wa3 = bch2(wa.w);
            h2 wb0, wb1, wb2, wb3;
            if (j1 < FOUT) {
                float4 wb = w1p[c];
                wb0 = bch2(wb.x); wb1 = bch2(wb.y); wb2 = bch2(wb.z); wb3 = bch2(wb.w);
            }
#pragma unroll
            for (int r = 0; r < 2; ++r) {
                const h2* ir = in + r * INP + 4 * c;
                a0[r] = fdot2f(wa0, ir[0], a0[r]);
                a0[r] = fdot2f(wa1, ir[1], a0[r]);
                a0[r] = fdot2f(wa2, ir[2], a0[r]);
                a0[r] = fdot2f(wa3, ir[3], a0[r]);
                if (j1 < FOUT) {
                    a1[r] = fdot2f(wb0, ir[0], a1[r]);
                    a1[r] = fdot2f(wb1, ir[1], a1[r]);
                    a1[r] = fdot2f(wb2, ir[2], a1[r]);
                    a1[r] = fdot2f(wb3, ir[3], a1[r]);
                }
            }
        }
#pragma unroll
        for (int r = 0; r < 2; ++r) {
            h2 pv = pk2(a0[r], (j1 < FOUT) ? a1[r] : 0.0f);
            if (RELU) pv = relu2(pv);       // packed relu; pads stay 0
            outp[r * OUTP + jp] = pv;
        }
    }
#pragma unroll
    for (int jp = JP; jp < OUTP; ++jp)
#pragma unroll
        for (int r = 0; r < 2; ++r) outp[r * OUTP + jp] = h2zero();
}

__global__ __launch_bounds__(NTHREADS, 8) void mlp_dot2d(
    const float* __restrict__ x,
    const float* __restrict__ W1, const float* __restrict__ B1,
    const float* __restrict__ W2, const float* __restrict__ B2,
    const float* __restrict__ W3, const float* __restrict__ B3,
    const float* __restrict__ W4, const float* __restrict__ B4,
    const float* __restrict__ W5, const float* __restrict__ B5,
    const float* __restrict__ W6, const float* __restrict__ B6,
    const float* __restrict__ W7, const float* __restrict__ B7,
    float* __restrict__ out, int nrows)
{
    __shared__ __fp16 sh[1840];
    __shared__ float  sb[76];
    const int t = threadIdx.x;

    stage_wh<30, 32, 24>(W1, sh + 0,    t);
    stage_wh<24, 24, 19>(W2, sh + 768,  t);
    stage_wh<19, 24, 14>(W3, sh + 1224, t);
    stage_wh<14, 16, 10>(W4, sh + 1560, t);
    stage_wh<10, 16, 6 >(W5, sh + 1720, t);
    stage_wh<6,  8,  2 >(W6, sh + 1816, t);
    stage_wh<2,  8,  1 >(W7, sh + 1832, t);
    if (t < 24) sb[0  + t] = B1[t];
    if (t < 19) sb[24 + t] = B2[t];
    if (t < 14) sb[43 + t] = B3[t];
    if (t < 10) sb[57 + t] = B4[t];
    if (t < 6)  sb[67 + t] = B5[t];
    if (t < 2)  sb[73 + t] = B6[t];
    if (t < 1)  sb[75 + t] = B7[t];
    __syncthreads();

    const int row0 = (blockIdx.x * NTHREADS + t) * 2;   // 2 adjacent rows
    if (row0 + 1 >= nrows) return;

    // ---- up-front x load: 240 B contiguous = 15 dwordx4, one tight burst ----
    h2 xq[2 * 16];                                      // [r][16], pair 15 = zero pad
    {
        const float4* xp = (const float4*)(x + (size_t)row0 * 30);
        float ta[60];
#pragma unroll
        for (int i = 0; i < 15; ++i) {
            float4 v = xp[i];
            ta[4 * i] = v.x; ta[4 * i + 1] = v.y; ta[4 * i + 2] = v.z; ta[4 * i + 3] = v.w;
        }
#pragma unroll
        for (int r = 0; r < 2; ++r) {
#pragma unroll
            for (int p = 0; p < 15; ++p)
                xq[r * 16 + p] = pk2(ta[30 * r + 2 * p], ta[30 * r + 2 * p + 1]);
            xq[r * 16 + 15] = h2zero();
        }
    }

    h2 h1[2 * 12];  layer_dot2<32, 24, 12, true>(sh + 0,    sb + 0,  xq,  h1);
    h2 h2a[2 * 12]; layer_dot2<24, 19, 12, true>(sh + 768,  sb + 24, h1,  h2a);
    h2 h3[2 * 8];   layer_dot2<24, 14, 8,  true>(sh + 1224, sb + 43, h2a, h3);
    h2 h4[2 * 8];   layer_dot2<16, 10, 8,  true>(sh + 1560, sb + 57, h3,  h4);
    h2 h5[2 * 4];   layer_dot2<16, 6,  4,  true>(sh + 1720, sb + 67, h4,  h5);
    h2 h6[2 * 1];   layer_dot2<8,  2,  1,  true>(sh + 1816, sb + 73, h5,  h6);

    // ---- layer 7: 2 -> 1, no relu ----
    const h2 w7 = *(const h2*)(sh + 1832);
    const float b7 = sb[75];
    float o0 = fdot2f(w7, h6[0], b7);
    float o1 = fdot2f(w7, h6[1], b7);

    *(float2*)(out + row0) = make_float2(o0, o1);
}

extern "C" void kernel_launch(void* const* d_in, const int* in_sizes, int n_in,
                              void* d_out, int out_size, void* d_ws, size_t ws_size,
                              hipStream_t stream) {
    const float* x = (const float*)d_in[0];
    int nrows = in_sizes[0] / 30;
    int pairs = nrows / 2;
    int blocks = (pairs + NTHREADS - 1) / NTHREADS;
    mlp_dot2d<<<blocks, NTHREADS, 0, stream>>>(
        x,
        (const float*)d_in[1],  (const float*)d_in[2],
        (const float*)d_in[3],  (const float*)d_in[4],
        (const float*)d_in[5],  (const float*)d_in[6],
        (const float*)d_in[7],  (const float*)d_in[8],
        (const float*)d_in[9],  (const float*)d_in[10],
        (const float*)d_in[11], (const float*)d_in[12],
        (const float*)d_in[13], (const float*)d_in[14],
        (float*)d_out, nrows);
}

// Round 19
// 48.936 us; speedup vs baseline: 1.1277x; 1.0127x over previous
//
#include <hip/hip_runtime.h>

// MLP 30->24->19->14->10->6->2->1 via MFMA (v_mfma_f32_32x32x16_f16).
// Per wave: one 32-row tile. D = W_eff * act: A-operand = weights (M=FOUT<=32,
// K=FIN padded), B-operand = activations^T (K x N=32 samples).
// Bias folded as extra K-slot: W_eff[m][FIN]=bias[m], act[FIN][:]=1.0.
// C/D layout (HW-verified, m74/m101): col=lane&31, row=(reg&3)+8*(reg>>2)+4*(lane>>5).
// A/B operand layout (standard): lane holds elem[m_or_n=lane&31][k=8*(lane>>5)+j].
// Inter-layer: D -> relu -> cvt_pkrtz -> shfl_xor(32)+select to build B-frags
// entirely in VALU (no LDS round-trip). Weights f16 in LDS, XOR-swizzled.
// Block = 256 thr = 4 waves = 128 rows; grid 8192 (exactly 4 blocks/CU).

#define NTHREADS 256

typedef __fp16       h2     __attribute__((ext_vector_type(2)));
typedef __fp16       half8  __attribute__((ext_vector_type(8)));
typedef float        f32x16 __attribute__((ext_vector_type(16)));
typedef unsigned int uint4v __attribute__((ext_vector_type(4)));

__device__ __forceinline__ h2 cpk(float a, float b) {
    return __builtin_bit_cast(h2, __builtin_amdgcn_cvt_pkrtz(a, b));
}
__device__ __forceinline__ h2 relu2(h2 v) {
    h2 z = {(__fp16)0.f, (__fp16)0.f};
#if __has_builtin(__builtin_elementwise_max)
    return __builtin_elementwise_max(v, z);
#else
    v.x = v.x > (__fp16)0.f ? v.x : (__fp16)0.f;
    v.y = v.y > (__fp16)0.f ? v.y : (__fp16)0.f;
    return v;
#endif
}
__device__ __forceinline__ unsigned ucast(h2 v) { return __builtin_bit_cast(unsigned, v); }

__device__ __forceinline__ f32x16 mfma_(half8 A, half8 B, f32x16 C) {
    return __builtin_amdgcn_mfma_f32_32x32x16_f16(A, B, C, 0, 0, 0);
}

// ---- weight staging: W_eff[m][k] f16, m padded to 32, k padded to KPAD ----
// swizzle: byte ^= (m&7)<<4 (bijective; spreads the per-m 16B frags over banks)
template <int FIN, int FOUT, int KPAD>
__device__ __forceinline__ void stageW(const float* __restrict__ W, const float* __restrict__ B,
                                       __fp16* __restrict__ sbase, int t) {
    for (int idx = t; idx < 32 * KPAD; idx += NTHREADS) {
        int m = idx / KPAD;
        int k = idx & (KPAD - 1);
        float v = 0.f;
        if (m < FOUT) {
            if (k < FIN) v = W[m * FIN + k];
            else if (k == FIN) v = B[m];
        }
        int byte = idx * 2;
        byte ^= (m & 7) << 4;
        *(__fp16*)((char*)sbase + byte) = (__fp16)v;
    }
}

// A-fragment read: lane holds W_eff[m=lane&31][k = ks*16 + 8*(lane>>5) + j]
__device__ __forceinline__ half8 ldA(const __fp16* base, int KPAD, int ks, int lane) {
    int m = lane & 31;
    int byte = (m * KPAD + ks * 16 + ((lane >> 5) & 1) * 8) * 2;
    byte ^= (m & 7) << 4;
    return __builtin_bit_cast(half8, *(const uint4v*)((const char*)base + byte));
}

// B-fragment from accumulator D, k-block regs R (0 or 8).
// POS = bias k-slot within this 16-wide block ([0,16)); POS<0 = none.
// Derivation (hb = lane>>5; t_i = relu(cpk(d[R+2i],d[R+2i+1]))):
//  lane's d regs carry features m = {R..R+3, R+8..R+11} + 4*hb (as k-values).
//  Wanted w_j = B k-pair (2j,2j+1) for hb=0 lanes / (8+2j,9+2j... ) i.e.
//  w0: lo=t0(lo), hi=t2(lo);  w1: lo=t1(lo), hi=t3(lo);
//  w2: lo=t0(hi), hi=t2(hi);  w3: lo=t1(hi), hi=t3(hi).
template <int R, int POS>
__device__ __forceinline__ half8 bfrag(const f32x16& d, int lane) {
    unsigned u0 = ucast(relu2(cpk(d[R + 0], d[R + 1])));
    unsigned u1 = ucast(relu2(cpk(d[R + 2], d[R + 3])));
    unsigned u2 = ucast(relu2(cpk(d[R + 4], d[R + 5])));
    unsigned u3 = ucast(relu2(cpk(d[R + 6], d[R + 7])));
    bool lo = (lane & 32) == 0;
    unsigned s0 = __shfl_xor(u0, 32), s1 = __shfl_xor(u1, 32);
    unsigned s2 = __shfl_xor(u2, 32), s3 = __shfl_xor(u3, 32);
    unsigned w0 = lo ? u0 : s2;
    unsigned w1 = lo ? u1 : s3;
    unsigned w2 = lo ? s0 : u2;
    unsigned w3 = lo ? s1 : u3;
    if constexpr (POS >= 0) {
        constexpr bool hiT = POS >= 8;                  // slot owned by hi lanes?
        constexpr int  p   = POS & 7;
        constexpr unsigned bits = (p & 1) ? 0x3C000000u : 0x00003C00u;  // f16 1.0
        bool sel = (((lane & 32) != 0) == hiT);
        unsigned ob = sel ? bits : 0u;
        if constexpr ((p >> 1) == 0) w0 |= ob;
        else if constexpr ((p >> 1) == 1) w1 |= ob;
        else if constexpr ((p >> 1) == 2) w2 |= ob;
        else w3 |= ob;
    }
    uint4v u = {w0, w1, w2, w3};
    return __builtin_bit_cast(half8, u);
}

__device__ __forceinline__ half8 packx(unsigned a, unsigned b, unsigned c, unsigned d) {
    uint4v u = {a, b, c, d};
    return __builtin_bit_cast(half8, u);
}

__global__ __launch_bounds__(NTHREADS, 4) void mlp_mfma(
    const float* __restrict__ x,
    const float* __restrict__ W1, const float* __restrict__ B1,
    const float* __restrict__ W2, const float* __restrict__ B2,
    const float* __restrict__ W3, const float* __restrict__ B3,
    const float* __restrict__ W4, const float* __restrict__ B4,
    const float* __restrict__ W5, const float* __restrict__ B5,
    const float* __restrict__ W6, const float* __restrict__ B6,
    const float* __restrict__ W7, const float* __restrict__ B7,
    float* __restrict__ out, int nrows)
{
    // weights: L1@0(32x32) L2@1024 L3@2048 L4@3072(32x16) L5@3584 L6@4096
    //          L7@4608 -> 5120 f16 = 10240 B
    __shared__ __align__(16) __fp16 shw[5120];
    __shared__ __align__(16) float  sxs[3848];   // 128 rows x 30 + 8 pad

    const int t    = threadIdx.x;
    const int lane = t & 63;
    const int wid  = t >> 6;
    const int hb   = (lane >> 5) & 1;

    stageW<30, 24, 32>(W1, B1, shw + 0,    t);
    stageW<24, 19, 32>(W2, B2, shw + 1024, t);
    stageW<19, 14, 32>(W3, B3, shw + 2048, t);
    stageW<14, 10, 16>(W4, B4, shw + 3072, t);
    stageW<10, 6,  16>(W5, B5, shw + 3584, t);
    stageW<6,  2,  16>(W6, B6, shw + 4096, t);
    stageW<2,  1,  16>(W7, B7, shw + 4608, t);

    // coalesced x slab: 128 rows * 30 f32 = 960 float4
    {
        const float4* gx = (const float4*)(x + (size_t)blockIdx.x * 3840);
        float4* sx4 = (float4*)sxs;
        for (int i = t; i < 960; i += NTHREADS) sx4[i] = gx[i];
        if (t < 8) sxs[3840 + t] = 0.f;
    }
    __syncthreads();

    // ---- x B-fragments for layer 1 (K=30, +bias-1.0 at k=30) ----
    const int    rl = wid * 32 + (lane & 31);
    const float* xr = sxs + rl * 30;
    float f0a[8], f1a[8];
    {
        const float2* p0 = (const float2*)(xr + hb * 8);
        float2 a = p0[0], b = p0[1], c = p0[2], d = p0[3];
        f0a[0] = a.x; f0a[1] = a.y; f0a[2] = b.x; f0a[3] = b.y;
        f0a[4] = c.x; f0a[5] = c.y; f0a[6] = d.x; f0a[7] = d.y;
        const float2* p1 = (const float2*)(xr + 16 + hb * 8);
        float2 e = p1[0], g = p1[1], h = p1[2], i = p1[3];
        f1a[0] = e.x; f1a[1] = e.y; f1a[2] = g.x; f1a[3] = g.y;
        f1a[4] = h.x; f1a[5] = h.y; f1a[6] = i.x; f1a[7] = i.y;
    }
    half8 Bx0 = packx(ucast(cpk(f0a[0], f0a[1])), ucast(cpk(f0a[2], f0a[3])),
                      ucast(cpk(f0a[4], f0a[5])), ucast(cpk(f0a[6], f0a[7])));
    // hi lanes' last word covers k=30,31: inject (1.0, 0.0); lo lanes k=22,23 real
    unsigned x13 = hb ? 0x00003C00u : ucast(cpk(f1a[6], f1a[7]));
    half8 Bx1 = packx(ucast(cpk(f1a[0], f1a[1])), ucast(cpk(f1a[2], f1a[3])),
                      ucast(cpk(f1a[4], f1a[5])), x13);

    const f32x16 z = {0.f,0.f,0.f,0.f, 0.f,0.f,0.f,0.f, 0.f,0.f,0.f,0.f, 0.f,0.f,0.f,0.f};

    // ---- layer 1 (K=32 in 2 steps) ----
    f32x16 a1 = mfma_(ldA(shw + 0, 32, 0, lane), Bx0, z);
    a1 = mfma_(ldA(shw + 0, 32, 1, lane), Bx1, a1);

    // ---- layer 2: FIN=24 -> block0 plain, block1 bias at POS=8 ----
    f32x16 a2 = mfma_(ldA(shw + 1024, 32, 0, lane), bfrag<0, -1>(a1, lane), z);
    a2 = mfma_(ldA(shw + 1024, 32, 1, lane), bfrag<8, 8>(a1, lane), a2);

    // ---- layer 3: FIN=19 -> block0 plain, block1 bias at POS=3 ----
    f32x16 a3 = mfma_(ldA(shw + 2048, 32, 0, lane), bfrag<0, -1>(a2, lane), z);
    a3 = mfma_(ldA(shw + 2048, 32, 1, lane), bfrag<8, 3>(a2, lane), a3);

    // ---- layers 4..7: single K=16 block each, bias at POS=FIN ----
    f32x16 a4 = mfma_(ldA(shw + 3072, 16, 0, lane), bfrag<0, 14>(a3, lane), z);
    f32x16 a5 = mfma_(ldA(shw + 3584, 16, 0, lane), bfrag<0, 10>(a4, lane), z);
    f32x16 a6 = mfma_(ldA(shw + 4096, 16, 0, lane), bfrag<0, 6>(a5, lane), z);
    f32x16 a7 = mfma_(ldA(shw + 4608, 16, 0, lane), bfrag<0, 2>(a6, lane), z);  // no relu on out

    // D7[m=0][n=lane&31] lives in reg 0 of lo lanes
    const int row0 = blockIdx.x * 128 + wid * 32;
    if (lane < 32) {
        int r = row0 + lane;
        if (r < nrows) out[r] = a7[0];
    }
}

extern "C" void kernel_launch(void* const* d_in, const int* in_sizes, int n_in,
                              void* d_out, int out_size, void* d_ws, size_t ws_size,
                              hipStream_t stream) {
    const float* x = (const float*)d_in[0];
    int nrows = in_sizes[0] / 30;
    int blocks = (nrows + 127) / 128;
    mlp_mfma<<<blocks, NTHREADS, 0, stream>>>(
        x,
        (const float*)d_in[1],  (const float*)d_in[2],
        (const float*)d_in[3],  (const float*)d_in[4],
        (const float*)d_in[5],  (const float*)d_in[6],
        (const float*)d_in[7],  (const float*)d_in[8],
        (const float*)d_in[9],  (const float*)d_in[10],
        (const float*)d_in[11], (const float*)d_in[12],
        (const float*)d_in[13], (const float*)d_in[14],
        (float*)d_out, nrows);
}

// Round 20
// 35.110 us; speedup vs baseline: 1.5718x; 1.3938x over previous
//
#include <hip/hip_runtime.h>

// MLP 30->24->19->14->10->6->2->1 via MFMA (v_mfma_f32_32x32x16_f16).
// R20 vs R19 (which was latency-bound: VGPR=40, all A-frags re-read from LDS
// just-in-time, 128 rows/block):
//  - A-fragments HOISTED to registers once per wave (10 frags x 4 VGPR).
//  - 4 slabs (512 rows) per block, grid 2048: weight staging amortized 4x.
//  - x slab double-buffered in LDS with async-stage split (T14): issue next
//    slab's 4 dwordx4 -> compute current tile -> ds_write -> one barrier.
//  - __launch_bounds__(256,3): 168 VGPR cap, ~12 waves/CU.
// Layouts (verified numerically in R19, absmax 1.95e-3):
//  C/D: col=lane&31, row=(reg&3)+8*(reg>>2)+4*(lane>>5).
//  A/B: lane holds elem[m_or_n=lane&31][k=16*ks+8*(lane>>5)+j].
//  Bias folded as extra K-slot (W_eff[m][FIN]=bias, act k=FIN = 1.0).

#define NTHREADS 256

typedef __fp16       h2     __attribute__((ext_vector_type(2)));
typedef __fp16       half8  __attribute__((ext_vector_type(8)));
typedef float        f32x16 __attribute__((ext_vector_type(16)));
typedef unsigned int uint4v __attribute__((ext_vector_type(4)));

__device__ __forceinline__ h2 cpk(float a, float b) {
    return __builtin_bit_cast(h2, __builtin_amdgcn_cvt_pkrtz(a, b));
}
__device__ __forceinline__ h2 relu2(h2 v) {
    h2 z = {(__fp16)0.f, (__fp16)0.f};
#if __has_builtin(__builtin_elementwise_max)
    return __builtin_elementwise_max(v, z);
#else
    v.x = v.x > (__fp16)0.f ? v.x : (__fp16)0.f;
    v.y = v.y > (__fp16)0.f ? v.y : (__fp16)0.f;
    return v;
#endif
}
__device__ __forceinline__ unsigned ucast(h2 v) { return __builtin_bit_cast(unsigned, v); }

__device__ __forceinline__ f32x16 mfma_(half8 A, half8 B, f32x16 C) {
    return __builtin_amdgcn_mfma_f32_32x32x16_f16(A, B, C, 0, 0, 0);
}

// ---- weight staging: W_eff[m][k] f16, m padded to 32, k padded to KPAD ----
template <int FIN, int FOUT, int KPAD>
__device__ __forceinline__ void stageW(const float* __restrict__ W, const float* __restrict__ B,
                                       __fp16* __restrict__ sbase, int t) {
    for (int idx = t; idx < 32 * KPAD; idx += NTHREADS) {
        int m = idx / KPAD;
        int k = idx & (KPAD - 1);
        float v = 0.f;
        if (m < FOUT) {
            if (k < FIN) v = W[m * FIN + k];
            else if (k == FIN) v = B[m];
        }
        int byte = idx * 2;
        byte ^= (m & 7) << 4;
        *(__fp16*)((char*)sbase + byte) = (__fp16)v;
    }
}

// A-fragment read: lane holds W_eff[m=lane&31][k = ks*16 + 8*(lane>>5) + j]
__device__ __forceinline__ half8 ldA(const __fp16* base, int KPAD, int ks, int lane) {
    int m = lane & 31;
    int byte = (m * KPAD + ks * 16 + ((lane >> 5) & 1) * 8) * 2;
    byte ^= (m & 7) << 4;
    return __builtin_bit_cast(half8, *(const uint4v*)((const char*)base + byte));
}

// B-fragment from accumulator D, k-block regs R (0 or 8); POS = bias slot.
template <int R, int POS>
__device__ __forceinline__ half8 bfrag(const f32x16& d, int lane) {
    unsigned u0 = ucast(relu2(cpk(d[R + 0], d[R + 1])));
    unsigned u1 = ucast(relu2(cpk(d[R + 2], d[R + 3])));
    unsigned u2 = ucast(relu2(cpk(d[R + 4], d[R + 5])));
    unsigned u3 = ucast(relu2(cpk(d[R + 6], d[R + 7])));
    bool lo = (lane & 32) == 0;
    unsigned s0 = __shfl_xor(u0, 32), s1 = __shfl_xor(u1, 32);
    unsigned s2 = __shfl_xor(u2, 32), s3 = __shfl_xor(u3, 32);
    unsigned w0 = lo ? u0 : s2;
    unsigned w1 = lo ? u1 : s3;
    unsigned w2 = lo ? s0 : u2;
    unsigned w3 = lo ? s1 : u3;
    if constexpr (POS >= 0) {
        constexpr bool hiT = POS >= 8;
        constexpr int  p   = POS & 7;
        constexpr unsigned bits = (p & 1) ? 0x3C000000u : 0x00003C00u;  // f16 1.0
        bool sel = (((lane & 32) != 0) == hiT);
        unsigned ob = sel ? bits : 0u;
        if constexpr ((p >> 1) == 0) w0 |= ob;
        else if constexpr ((p >> 1) == 1) w1 |= ob;
        else if constexpr ((p >> 1) == 2) w2 |= ob;
        else w3 |= ob;
    }
    uint4v u = {w0, w1, w2, w3};
    return __builtin_bit_cast(half8, u);
}

__device__ __forceinline__ half8 packx(unsigned a, unsigned b, unsigned c, unsigned d) {
    uint4v u = {a, b, c, d};
    return __builtin_bit_cast(half8, u);
}

#define SLABS 4            // 128-row slabs per block

__global__ __launch_bounds__(NTHREADS, 3) void mlp_mfma2(
    const float* __restrict__ x,
    const float* __restrict__ W1, const float* __restrict__ B1,
    const float* __restrict__ W2, const float* __restrict__ B2,
    const float* __restrict__ W3, const float* __restrict__ B3,
    const float* __restrict__ W4, const float* __restrict__ B4,
    const float* __restrict__ W5, const float* __restrict__ B5,
    const float* __restrict__ W6, const float* __restrict__ B6,
    const float* __restrict__ W7, const float* __restrict__ B7,
    float* __restrict__ out, int nrows)
{
    __shared__ __align__(16) __fp16 shw[5120];        // weights (10.2 KB)
    __shared__ __align__(16) float  sx[2][3840];      // 2 x 128-row slab (30.7 KB)

    const int t    = threadIdx.x;
    const int lane = t & 63;
    const int wid  = t >> 6;
    const int hb   = (lane >> 5) & 1;

    stageW<30, 24, 32>(W1, B1, shw + 0,    t);
    stageW<24, 19, 32>(W2, B2, shw + 1024, t);
    stageW<19, 14, 32>(W3, B3, shw + 2048, t);
    stageW<14, 10, 16>(W4, B4, shw + 3072, t);
    stageW<10, 6,  16>(W5, B5, shw + 3584, t);
    stageW<6,  2,  16>(W6, B6, shw + 4096, t);
    stageW<2,  1,  16>(W7, B7, shw + 4608, t);

    // stage slab 0 (coalesced 960 float4)
    {
        const float4* gx = (const float4*)(x + (size_t)blockIdx.x * (SLABS * 3840));
        float4* s0 = (float4*)sx[0];
        for (int i = t; i < 960; i += NTHREADS) s0[i] = gx[i];
    }
    __syncthreads();

    // ---- hoist all A-fragments into registers (10 x 4 VGPR) ----
    const half8 A10 = ldA(shw + 0,    32, 0, lane), A11 = ldA(shw + 0,    32, 1, lane);
    const half8 A20 = ldA(shw + 1024, 32, 0, lane), A21 = ldA(shw + 1024, 32, 1, lane);
    const half8 A30 = ldA(shw + 2048, 32, 0, lane), A31 = ldA(shw + 2048, 32, 1, lane);
    const half8 A4  = ldA(shw + 3072, 16, 0, lane);
    const half8 A5  = ldA(shw + 3584, 16, 0, lane);
    const half8 A6  = ldA(shw + 4096, 16, 0, lane);
    const half8 A7  = ldA(shw + 4608, 16, 0, lane);

    const f32x16 z = {0.f,0.f,0.f,0.f, 0.f,0.f,0.f,0.f, 0.f,0.f,0.f,0.f, 0.f,0.f,0.f,0.f};

    for (int s = 0; s < SLABS; ++s) {
        // ---- T14 async-stage: issue next slab's loads before compute ----
        float4 pf0, pf1, pf2, pf3;
        const bool hp3 = t < (960 - 3 * NTHREADS);            // 192 threads
        if (s < SLABS - 1) {
            const float4* gx = (const float4*)(x + ((size_t)blockIdx.x * SLABS + s + 1) * 3840);
            pf0 = gx[t];
            pf1 = gx[t + NTHREADS];
            pf2 = gx[t + 2 * NTHREADS];
            if (hp3) pf3 = gx[t + 3 * NTHREADS];
        }

        // ---- compute one 32-row tile from current slab ----
        const float* xs = sx[s & 1];
        const float* xr = xs + (wid * 32 + (lane & 31)) * 30;
        float f0a[8], f1a[8];
        {
            const float2* p0 = (const float2*)(xr + hb * 8);
            float2 a = p0[0], b = p0[1], c = p0[2], d = p0[3];
            f0a[0] = a.x; f0a[1] = a.y; f0a[2] = b.x; f0a[3] = b.y;
            f0a[4] = c.x; f0a[5] = c.y; f0a[6] = d.x; f0a[7] = d.y;
            const float2* p1 = (const float2*)(xr + 16 + hb * 8);
            float2 e = p1[0], g = p1[1], h = p1[2], i = p1[3];
            f1a[0] = e.x; f1a[1] = e.y; f1a[2] = g.x; f1a[3] = g.y;
            f1a[4] = h.x; f1a[5] = h.y; f1a[6] = i.x; f1a[7] = i.y;
        }
        half8 Bx0 = packx(ucast(cpk(f0a[0], f0a[1])), ucast(cpk(f0a[2], f0a[3])),
                          ucast(cpk(f0a[4], f0a[5])), ucast(cpk(f0a[6], f0a[7])));
        unsigned x13 = hb ? 0x00003C00u : ucast(cpk(f1a[6], f1a[7]));  // bias 1.0 @ k=30
        half8 Bx1 = packx(ucast(cpk(f1a[0], f1a[1])), ucast(cpk(f1a[2], f1a[3])),
                          ucast(cpk(f1a[4], f1a[5])), x13);

        f32x16 a1 = mfma_(A10, Bx0, z);
        a1 = mfma_(A11, Bx1, a1);
        f32x16 a2 = mfma_(A20, bfrag<0, -1>(a1, lane), z);
        a2 = mfma_(A21, bfrag<8, 8>(a1, lane), a2);
        f32x16 a3 = mfma_(A30, bfrag<0, -1>(a2, lane), z);
        a3 = mfma_(A31, bfrag<8, 3>(a2, lane), a3);
        f32x16 a4 = mfma_(A4, bfrag<0, 14>(a3, lane), z);
        f32x16 a5 = mfma_(A5, bfrag<0, 10>(a4, lane), z);
        f32x16 a6 = mfma_(A6, bfrag<0, 6>(a5, lane), z);
        f32x16 a7 = mfma_(A7, bfrag<0, 2>(a6, lane), z);

        const int row0 = (blockIdx.x * SLABS + s) * 128 + wid * 32;
        if (lane < 32) {
            int r = row0 + lane;
            if (r < nrows) out[r] = a7[0];
        }

        // ---- write prefetched slab into the other buffer, then barrier ----
        if (s < SLABS - 1) {
            float4* so = (float4*)sx[(s + 1) & 1];
            so[t] = pf0;
            so[t + NTHREADS] = pf1;
            so[t + 2 * NTHREADS] = pf2;
            if (hp3) so[t + 3 * NTHREADS] = pf3;
        }
        __syncthreads();
    }
}

extern "C" void kernel_launch(void* const* d_in, const int* in_sizes, int n_in,
                              void* d_out, int out_size, void* d_ws, size_t ws_size,
                              hipStream_t stream) {
    const float* x = (const float*)d_in[0];
    int nrows = in_sizes[0] / 30;
    int blocks = (nrows + SLABS * 128 - 1) / (SLABS * 128);
    mlp_mfma2<<<blocks, NTHREADS, 0, stream>>>(
        x,
        (const float*)d_in[1],  (const float*)d_in[2],
        (const float*)d_in[3],  (const float*)d_in[4],
        (const float*)d_in[5],  (const float*)d_in[6],
        (const float*)d_in[7],  (const float*)d_in[8],
        (const float*)d_in[9],  (const float*)d_in[10],
        (const float*)d_in[11], (const float*)d_in[12],
        (const float*)d_in[13], (const float*)d_in[14],
        (float*)d_out, nrows);
}